// Round 1
// 229.163 us; speedup vs baseline: 1.0723x; 1.0723x over previous
//
#include <hip/hip_runtime.h>
#include <stdint.h>

#define N_NODES 100000
#define N_EDGES 1000000
#define NBUCK 98    // ceil(N_NODES / 1024)
#define CAP 12288   // per-bucket part capacity; counts ~ Poisson(10240), +20 sigma

typedef __attribute__((ext_vector_type(8))) __bf16 bf16x8;
typedef __attribute__((ext_vector_type(4))) float f32x4;

// ---------- bf16 helpers ----------
static __device__ __forceinline__ float bf2f(unsigned short u) {
    return __uint_as_float(((unsigned int)u) << 16);
}
static __device__ __forceinline__ unsigned short f2bf(float f) {
    unsigned int u = __float_as_uint(f);
    unsigned int r = (u + 0x7FFFu + ((u >> 16) & 1u)) >> 16;  // RNE
    return (unsigned short)r;
}
static __device__ __forceinline__ float4 ld4_half(const unsigned short* p) {
    ushort4 u = *(const ushort4*)p;
    return make_float4(bf2f(u.x), bf2f(u.y), bf2f(u.z), bf2f(u.w));
}
// pack 8 f32 -> 8 bf16, one 16B store
static __device__ __forceinline__ void st8_half(unsigned short* p, const float* f) {
    int4 u;
    u.x = (int)(((unsigned)f2bf(f[0])) | (((unsigned)f2bf(f[1])) << 16));
    u.y = (int)(((unsigned)f2bf(f[2])) | (((unsigned)f2bf(f[3])) << 16));
    u.z = (int)(((unsigned)f2bf(f[4])) | (((unsigned)f2bf(f[5])) << 16));
    u.w = (int)(((unsigned)f2bf(f[6])) | (((unsigned)f2bf(f[7])) << 16));
    *(int4*)p = u;
}

// ---------- dynamic-dtype external loads (flag: 1 = bf16 memory, 0 = f32) ----------
static __device__ __forceinline__ float ldf(const void* p, size_t i, int bf) {
    return bf ? bf2f(((const unsigned short*)p)[i]) : ((const float*)p)[i];
}

// ---------- dtype probe + cursor init ----------
__global__ __launch_bounds__(256) void detect_kernel(const unsigned short* __restrict__ xs,
                                                     int* __restrict__ flag,
                                                     int* __restrict__ bcursor) {
    __shared__ int sz;
    if (threadIdx.x == 0) sz = 0;
    __syncthreads();
    int z = 0;
    for (int i = threadIdx.x; i < 1024; i += 256) {
        float av = fabsf(bf2f(xs[2 * i]));
        if (!(av <= 1048576.0f) || (av != 0.0f && av < 9.5367431640625e-07f)) z++;
    }
    atomicAdd(&sz, z);
    if (threadIdx.x < NBUCK) bcursor[threadIdx.x] = threadIdx.x * CAP;
    __syncthreads();
    if (threadIdx.x == 0) *flag = (sz > 256) ? 0 : 1;
}

// ---------- partition edges into fixed-capacity bucket regions ----------
// rec = {src | dst_local<<17, val_bits}; region b = part[b*CAP ...)
__global__ __launch_bounds__(256) void part_kernel(const int* __restrict__ src,
                                                   const int* __restrict__ dst,
                                                   const void* __restrict__ val,
                                                   int* __restrict__ bcursor,
                                                   int2* __restrict__ part,
                                                   const int* __restrict__ flagp) {
    __shared__ int cnt[NBUCK];
    __shared__ int base[NBUCK];
    const int bf = *flagp;
    const int tid = threadIdx.x;
    const int e0 = blockIdx.x * 2048;
    for (int i = tid; i < NBUCK; i += 256) cnt[i] = 0;
    __syncthreads();
    int rank[8], bkt[8], pk[8], vb[8];
#pragma unroll
    for (int i = 0; i < 8; ++i) {
        int e = e0 + i * 256 + tid;
        bkt[i] = -1;
        if (e < N_EDGES) {
            int d = dst[e];
            int b = d >> 10;
            bkt[i] = b;
            pk[i] = src[e] | ((d & 1023) << 17);
            vb[i] = __float_as_int(ldf(val, e, bf));
            rank[i] = atomicAdd(&cnt[b], 1);
        }
    }
    __syncthreads();
    for (int i = tid; i < NBUCK; i += 256) {
        int c = cnt[i];
        base[i] = c ? atomicAdd(&bcursor[i], c) : 0;
    }
    __syncthreads();
#pragma unroll
    for (int i = 0; i < 8; ++i) {
        if (bkt[i] >= 0) part[(size_t)base[bkt[i]] + rank[i]] = make_int2(pk[i], vb[i]);
    }
}

// ---------- place: per-bucket row histogram+scan, compact csr_rec + row_start ----------
// Each block redundantly prefix-scans the 98 bucket counts (from bcursor) itself.
__global__ __launch_bounds__(512) void place_kernel(const int* __restrict__ bcursor,
                                                    const int2* __restrict__ part,
                                                    int* __restrict__ row_start,
                                                    int2* __restrict__ csr_rec) {
    __shared__ int cnt[1024];
    __shared__ int sums[512];
    __shared__ int sh_s, sh_cnt, sh_total;
    const int tid = threadIdx.x;
    const int b = blockIdx.x;
    const int row0 = b << 10;
    const int nrows = min(1024, N_NODES - row0);

    // bucket-count exclusive prefix (redundant, trivial)
    if (tid < 128) sums[tid] = (tid < NBUCK) ? (bcursor[tid] - tid * CAP) : 0;
    __syncthreads();
    for (int off = 1; off < 128; off <<= 1) {
        int t = 0;
        if (tid < 128 && tid >= off) t = sums[tid - off];
        __syncthreads();
        if (tid < 128 && tid >= off) sums[tid] += t;
        __syncthreads();
    }
    if (tid == 0) {
        sh_s = (b > 0) ? sums[b - 1] : 0;
        sh_cnt = bcursor[b] - b * CAP;
        sh_total = sums[NBUCK - 1];
    }
    __syncthreads();
    const int s = sh_s;          // global csr_rec start of this bucket
    const int cb = sh_cnt;       // edges in this bucket
    const int ps = b * CAP;      // part region start
    const int total = sh_total;

    for (int i = tid; i < 1024; i += 512) cnt[i] = 0;
    __syncthreads();
    for (int j = tid; j < cb; j += 512) {
        unsigned p = (unsigned)part[ps + j].x;
        atomicAdd(&cnt[p >> 17], 1);
    }
    __syncthreads();
    int a0 = cnt[2 * tid], a1 = cnt[2 * tid + 1];
    int ts = a0 + a1;
    sums[tid] = ts;
    __syncthreads();
    for (int off = 1; off < 512; off <<= 1) {
        int t = 0;
        if (tid >= off) t = sums[tid - off];
        __syncthreads();
        if (tid >= off) sums[tid] += t;
        __syncthreads();
    }
    int excl = sums[tid] - ts;
    cnt[2 * tid] = s + excl;          // running cursors (global positions)
    cnt[2 * tid + 1] = s + excl + a0;
    if (2 * tid < nrows)     row_start[row0 + 2 * tid] = s + excl;
    if (2 * tid + 1 < nrows) row_start[row0 + 2 * tid + 1] = s + excl + a0;
    if (b == NBUCK - 1 && tid == 0) row_start[N_NODES] = total;
    __syncthreads();
    for (int j = tid; j < cb; j += 512) {
        int2 r = part[ps + j];
        unsigned p = (unsigned)r.x;
        int pos = atomicAdd(&cnt[p >> 17], 1);
        csr_rec[pos] = make_int2((int)(p & 0x1FFFFu), r.y);
    }
}

// ---------- single-row gather: 8 bf16 cols per lane, chunk of 4 edges ----------
// RS = support row stride in shorts. Low VGPR (sp[4]+r[4]+a[8]) to keep 8 blocks/CU.
template <int RS>
static __device__ __forceinline__ void row_gather(const unsigned short* __restrict__ supc,
                                                  const int2* __restrict__ csr_rec,
                                                  int s, int e, float a[8]) {
    if (s >= e) return;
    int2 r[4];
#pragma unroll
    for (int t = 0; t < 4; ++t) r[t] = csr_rec[min(s + t, e - 1)];
    for (int j = s; j < e; j += 4) {
        int4 sp[4];
#pragma unroll
        for (int t = 0; t < 4; ++t) sp[t] = *(const int4*)(supc + (size_t)r[t].x * RS);
        float wv[4];
#pragma unroll
        for (int t = 0; t < 4; ++t) wv[t] = (j + t < e) ? __int_as_float(r[t].y) : 0.0f;
        int jn = j + 4;
        if (jn < e) {
#pragma unroll
            for (int t = 0; t < 4; ++t) r[t] = csr_rec[min(jn + t, e - 1)];
        }
#pragma unroll
        for (int t = 0; t < 4; ++t) {
            float w = wv[t];
            int q[4] = {sp[t].x, sp[t].y, sp[t].z, sp[t].w};
#pragma unroll
            for (int c = 0; c < 4; ++c) {
                float flo = __uint_as_float(((unsigned)q[c]) << 16);
                float fhi = __uint_as_float(((unsigned)q[c]) & 0xffff0000u);
                a[2 * c]     += w * flo;
                a[2 * c + 1] += w * fhi;
            }
        }
    }
}

// ---------- MFMA GEMM (layer 1): one 64-row tile per block, A direct from global ----------
template <int K, int M, bool DYNIN>
__global__ __launch_bounds__(256) void mgemm_kernel(const void* __restrict__ hv_,
                                                    const void* __restrict__ W,
                                                    unsigned short* __restrict__ out,
                                                    const int* __restrict__ flagp) {
    constexpr int KP = K + 8;
    constexpr int NC = M / 16;
    constexpr int NK = K / 32;

    __shared__ unsigned short wt[M][KP];  // W transposed

    const int bf = *flagp;
    const int tid = threadIdx.x;

    for (int i = tid; i < K * M; i += 256) {
        int k = i / M, m = i % M;
        wt[m][k] = f2bf(ldf(W, i, bf));
    }
    __syncthreads();

    const int lane = tid & 63;
    const int qd = lane >> 4;
    const int ln = lane & 15;
    const int wrow = (tid >> 6) * 16;
    const int tile = blockIdx.x;

    const int row = tile * 64 + wrow + ln;
    const bool ok = row < N_NODES;

    f32x4 acc[NC];
#pragma unroll
    for (int c = 0; c < NC; ++c) acc[c] = (f32x4){0.f, 0.f, 0.f, 0.f};

#pragma unroll
    for (int ks = 0; ks < NK; ++ks) {
        bf16x8 a;
        if (ok) {
            const size_t base = (size_t)row * K + ks * 32 + qd * 8;
            if (DYNIN && !bf) {
                const float* xp = (const float*)hv_ + base;
                float4 f0 = *(const float4*)xp;
                float4 f1 = *(const float4*)(xp + 4);
                ushort4 uu[2];
                uu[0].x = f2bf(f0.x); uu[0].y = f2bf(f0.y); uu[0].z = f2bf(f0.z); uu[0].w = f2bf(f0.w);
                uu[1].x = f2bf(f1.x); uu[1].y = f2bf(f1.y); uu[1].z = f2bf(f1.z); uu[1].w = f2bf(f1.w);
                a = *(const bf16x8*)uu;
            } else {
                a = *(const bf16x8*)((const unsigned short*)hv_ + base);
            }
        } else {
            a = (bf16x8)(__bf16)0.0f;
        }
#pragma unroll
        for (int c = 0; c < NC; ++c) {
            bf16x8 b = *(const bf16x8*)&wt[c * 16 + ln][ks * 32 + qd * 8];
            acc[c] = __builtin_amdgcn_mfma_f32_16x16x32_bf16(a, b, acc[c], 0, 0, 0);
        }
    }

#pragma unroll
    for (int c = 0; c < NC; ++c) {
#pragma unroll
        for (int r = 0; r < 4; ++r) {
            int orow = tile * 64 + wrow + qd * 4 + r;
            if (orow < N_NODES) out[(size_t)orow * M + c * 16 + ln] = f2bf(acc[c][r]);
        }
    }
}

// ---------- Fused: agg = relu(spmm(support)+bias); out = agg @ W  (K=64 fixed) ----------
// Gather: 32 groups x 8 lanes, 1 row per group per pass, 2 passes -> 64-row tile.
// __launch_bounds__(256,8): cap VGPR at 64 so all 1563 blocks are co-resident (8/CU).
template <int MOUT>
__global__ __launch_bounds__(256, 8) void fused_kernel(const unsigned short* __restrict__ support,
                                                       const int* __restrict__ row_start,
                                                       const int2* __restrict__ csr_rec,
                                                       const void* __restrict__ bias,
                                                       const void* __restrict__ W,
                                                       unsigned short* __restrict__ out,
                                                       const int* __restrict__ flagp) {
    constexpr int K = 64, KP = 72;
    constexpr int NC = MOUT / 16;
    constexpr int NK = 2;

    __shared__ unsigned short agg[64][KP];
    __shared__ unsigned short wt[MOUT][KP];

    const int bf = *flagp;
    const int tid = threadIdx.x;

    for (int i = tid; i < K * MOUT; i += 256) {
        int k = i / MOUT, m = i % MOUT;
        wt[m][k] = f2bf(ldf(W, i, bf));
    }
    // no barrier here: gather phase doesn't read wt; W-stage latency hides under gather

    const int lane = tid & 63;
    const int qd = lane >> 4;
    const int ln = lane & 15;
    const int wrow = (tid >> 6) * 16;

    const int grp = tid >> 3;   // 32 groups of 8 lanes; 1 row each per pass
    const int cc = tid & 7;     // cols cc*8..cc*8+7
    float bias8[8];
#pragma unroll
    for (int c = 0; c < 8; ++c) bias8[c] = ldf(bias, cc * 8 + c, bf);
    const unsigned short* supc = support + cc * 8;

    const int tile = blockIdx.x;
#pragma unroll
    for (int p = 0; p < 2; ++p) {
        const int row = tile * 64 + p * 32 + grp;
        int s = row_start[min(row, N_NODES)];
        int e = row_start[min(row + 1, N_NODES)];
        float a[8];
#pragma unroll
        for (int c = 0; c < 8; ++c) a[c] = bias8[c];
        row_gather<64>(supc, csr_rec, s, e, a);
#pragma unroll
        for (int c = 0; c < 8; ++c) a[c] = fmaxf(a[c], 0.f);
        st8_half(&agg[p * 32 + grp][cc * 8], a);
    }
    __syncthreads();

    f32x4 macc[NC];
#pragma unroll
    for (int c = 0; c < NC; ++c) macc[c] = (f32x4){0.f, 0.f, 0.f, 0.f};
#pragma unroll
    for (int ks = 0; ks < NK; ++ks) {
        bf16x8 a = *(const bf16x8*)&agg[wrow + ln][ks * 32 + qd * 8];
#pragma unroll
        for (int c = 0; c < NC; ++c) {
            bf16x8 b = *(const bf16x8*)&wt[c * 16 + ln][ks * 32 + qd * 8];
            macc[c] = __builtin_amdgcn_mfma_f32_16x16x32_bf16(a, b, macc[c], 0, 0, 0);
        }
    }

#pragma unroll
    for (int c = 0; c < NC; ++c) {
#pragma unroll
        for (int r = 0; r < 4; ++r) {
            int orow = tile * 64 + wrow + qd * 4 + r;
            if (orow < N_NODES) out[(size_t)orow * MOUT + c * 16 + ln] = f2bf(macc[c][r]);
        }
    }
}

// ---------- final SpMM (M=16): 2 lanes x 16B per row, 1 row per group, 128 rows/block ----------
template <bool DYNOUT>
__global__ __launch_bounds__(256, 8) void spmm16_kernel(const unsigned short* __restrict__ support,
                                                        const int* __restrict__ row_start,
                                                        const int2* __restrict__ csr_rec,
                                                        const void* __restrict__ bias,
                                                        void* __restrict__ out_,
                                                        const int* __restrict__ flagp) {
    constexpr int M = 16;
    int bf = *flagp;
    int tid = threadIdx.x;
    int grp = tid >> 1;           // 128 groups x 1 row = 128 rows per block
    int cc = tid & 1;             // cols cc*8..cc*8+7
    int row = blockIdx.x * 128 + grp;
    if (row >= N_NODES) return;
    int s = row_start[row];
    int e = row_start[row + 1];
    float a[8];
#pragma unroll
    for (int c = 0; c < 8; ++c) a[c] = ldf(bias, cc * 8 + c, bf);
    row_gather<16>(support + cc * 8, csr_rec, s, e, a);
    if (DYNOUT && !bf) {
        float* op = (float*)out_ + (size_t)row * M + cc * 8;
        *(float4*)op = make_float4(a[0], a[1], a[2], a[3]);
        *(float4*)(op + 4) = make_float4(a[4], a[5], a[6], a[7]);
    } else {
        st8_half((unsigned short*)out_ + (size_t)row * M + cc * 8, a);
    }
}

extern "C" void kernel_launch(void* const* d_in, const int* in_sizes, int n_in,
                              void* d_out, int out_size, void* d_ws, size_t ws_size,
                              hipStream_t stream) {
    (void)in_sizes; (void)n_in; (void)out_size; (void)ws_size;
    const void* x  = d_in[0];
    const void* ev = d_in[1];
    const void* W1 = d_in[2];
    const void* b1 = d_in[3];
    const void* W2 = d_in[4];
    const void* b2 = d_in[5];
    const void* W3 = d_in[6];
    const void* b3 = d_in[7];
    const int* esrc = (const int*)d_in[8];
    const int* edst = (const int*)d_in[9];

    // workspace (~34 MB)
    char* ws = (char*)d_ws;
    size_t off = 0;
    auto alloc = [&](size_t bytes) -> void* {
        void* p = ws + off;
        off = (off + bytes + 255) & ~(size_t)255;
        return p;
    };
    unsigned short* A = (unsigned short*)alloc((size_t)N_NODES * 64 * 2);  // support1 / A3
    unsigned short* B = (unsigned short*)alloc((size_t)N_NODES * 64 * 2);  // A2
    int* row_start  = (int*)alloc((size_t)(N_NODES + 1) * 4);
    int* bcursor    = (int*)alloc(512);
    int2* csr_rec   = (int2*)alloc((size_t)N_EDGES * 8);
    int* flagp      = (int*)alloc(256);
    // part[] (9.6 MB = 98*CAP*8) aliases A (12.8 MB): dead before mgemm1 writes A
    int2* part      = (int2*)A;

    // ---- dtype probe + cursor init ----
    detect_kernel<<<1, 256, 0, stream>>>((const unsigned short*)x, flagp, bcursor);

    // ---- CSR build: partition -> place (compact) ----
    part_kernel<<<(N_EDGES + 2047) / 2048, 256, 0, stream>>>(esrc, edst, ev, bcursor, part, flagp);
    place_kernel<<<NBUCK, 512, 0, stream>>>(bcursor, part, row_start, csr_rec);

    const int NT = (N_NODES + 63) / 64;  // 1563

    // ---- layer 1: A = x @ W1 ----
    mgemm_kernel<128, 64, true><<<NT, 256, 0, stream>>>(x, W1, A, flagp);
    // ---- layer 1 agg + layer 2 gemm fused: B = relu(spmm(A)+b1) @ W2 ----
    fused_kernel<64><<<NT, 256, 0, stream>>>(A, row_start, csr_rec, b1, W2, B, flagp);
    // ---- layer 2 agg + layer 3 gemm fused: A(=A3) = relu(spmm(B)+b2) @ W3 ----
    fused_kernel<16><<<NT, 256, 0, stream>>>(B, row_start, csr_rec, b2, W3, A, flagp);
    // ---- final aggregation: out = spmm(A3) + b3 ----
    spmm16_kernel<true><<<(N_NODES + 127) / 128, 256, 0, stream>>>(A, row_start, csr_rec, b3, d_out, flagp);
}

// Round 2
// 226.175 us; speedup vs baseline: 1.0865x; 1.0132x over previous
//
#include <hip/hip_runtime.h>
#include <stdint.h>

#define N_NODES 100000
#define N_EDGES 1000000
#define NBUCK 196   // ceil(N_NODES / 512)
#define CAP 6656    // per-bucket part capacity; counts ~ Poisson(5120), +21 sigma

typedef __attribute__((ext_vector_type(8))) __bf16 bf16x8;
typedef __attribute__((ext_vector_type(4))) float f32x4;

// ---------- bf16 helpers ----------
static __device__ __forceinline__ float bf2f(unsigned short u) {
    return __uint_as_float(((unsigned int)u) << 16);
}
static __device__ __forceinline__ unsigned short f2bf(float f) {
    unsigned int u = __float_as_uint(f);
    unsigned int r = (u + 0x7FFFu + ((u >> 16) & 1u)) >> 16;  // RNE
    return (unsigned short)r;
}
// pack 8 f32 -> 8 bf16, one 16B store
static __device__ __forceinline__ void st8_half(unsigned short* p, const float* f) {
    int4 u;
    u.x = (int)(((unsigned)f2bf(f[0])) | (((unsigned)f2bf(f[1])) << 16));
    u.y = (int)(((unsigned)f2bf(f[2])) | (((unsigned)f2bf(f[3])) << 16));
    u.z = (int)(((unsigned)f2bf(f[4])) | (((unsigned)f2bf(f[5])) << 16));
    u.w = (int)(((unsigned)f2bf(f[6])) | (((unsigned)f2bf(f[7])) << 16));
    *(int4*)p = u;
}

// ---------- dynamic-dtype external loads (flag: 1 = bf16 memory, 0 = f32) ----------
static __device__ __forceinline__ float ldf(const void* p, size_t i, int bf) {
    return bf ? bf2f(((const unsigned short*)p)[i]) : ((const float*)p)[i];
}

// ---------- dtype probe + cursor init ----------
__global__ __launch_bounds__(256) void detect_kernel(const unsigned short* __restrict__ xs,
                                                     int* __restrict__ flag,
                                                     int* __restrict__ bcursor) {
    __shared__ int sz;
    if (threadIdx.x == 0) sz = 0;
    __syncthreads();
    int z = 0;
    for (int i = threadIdx.x; i < 1024; i += 256) {
        float av = fabsf(bf2f(xs[2 * i]));
        if (!(av <= 1048576.0f) || (av != 0.0f && av < 9.5367431640625e-07f)) z++;
    }
    atomicAdd(&sz, z);
    if (threadIdx.x < NBUCK) bcursor[threadIdx.x] = threadIdx.x * CAP;
    __syncthreads();
    if (threadIdx.x == 0) *flag = (sz > 256) ? 0 : 1;
}

// ---------- partition edges into fixed-capacity bucket regions ----------
// rec = {src | dst_local<<17, val_bits}; region b = part[b*CAP ...); bucket = dst>>9
__global__ __launch_bounds__(256) void part_kernel(const int* __restrict__ src,
                                                   const int* __restrict__ dst,
                                                   const void* __restrict__ val,
                                                   int* __restrict__ bcursor,
                                                   int2* __restrict__ part,
                                                   const int* __restrict__ flagp) {
    __shared__ int cnt[NBUCK];
    __shared__ int base[NBUCK];
    const int bf = *flagp;
    const int tid = threadIdx.x;
    const int e0 = blockIdx.x * 2048;
    for (int i = tid; i < NBUCK; i += 256) cnt[i] = 0;
    __syncthreads();
    int rank[8], bkt[8], pk[8], vb[8];
#pragma unroll
    for (int i = 0; i < 8; ++i) {
        int e = e0 + i * 256 + tid;
        bkt[i] = -1;
        if (e < N_EDGES) {
            int d = dst[e];
            int b = d >> 9;
            bkt[i] = b;
            pk[i] = src[e] | ((d & 511) << 17);
            vb[i] = __float_as_int(ldf(val, e, bf));
            rank[i] = atomicAdd(&cnt[b], 1);
        }
    }
    __syncthreads();
    for (int i = tid; i < NBUCK; i += 256) {
        int c = cnt[i];
        base[i] = c ? atomicAdd(&bcursor[i], c) : 0;
    }
    __syncthreads();
#pragma unroll
    for (int i = 0; i < 8; ++i) {
        if (bkt[i] >= 0) part[(size_t)base[bkt[i]] + rank[i]] = make_int2(pk[i], vb[i]);
    }
}

// ---------- place: per-bucket (512 rows) histogram+scan, compact csr_rec + row_start ----------
// Each block redundantly prefix-scans the 196 bucket counts (from bcursor) itself.
__global__ __launch_bounds__(512) void place_kernel(const int* __restrict__ bcursor,
                                                    const int2* __restrict__ part,
                                                    int* __restrict__ row_start,
                                                    int2* __restrict__ csr_rec) {
    __shared__ int cnt[512];
    __shared__ int sums[512];
    __shared__ int sh_s, sh_cnt, sh_total;
    const int tid = threadIdx.x;
    const int b = blockIdx.x;
    const int row0 = b << 9;
    const int nrows = min(512, N_NODES - row0);

    // bucket-count exclusive prefix over 196 buckets (redundant per block, trivial)
    if (tid < 256) sums[tid] = (tid < NBUCK) ? (bcursor[tid] - tid * CAP) : 0;
    __syncthreads();
    for (int off = 1; off < 256; off <<= 1) {
        int t = 0;
        if (tid < 256 && tid >= off) t = sums[tid - off];
        __syncthreads();
        if (tid < 256 && tid >= off) sums[tid] += t;
        __syncthreads();
    }
    if (tid == 0) {
        sh_s = (b > 0) ? sums[b - 1] : 0;
        sh_cnt = bcursor[b] - b * CAP;
        sh_total = sums[NBUCK - 1];
    }
    __syncthreads();
    const int s = sh_s;          // global csr_rec start of this bucket
    const int cb = sh_cnt;       // edges in this bucket
    const int ps = b * CAP;      // part region start
    const int total = sh_total;

    cnt[tid] = 0;
    __syncthreads();
    for (int j = tid; j < cb; j += 512) {
        unsigned p = (unsigned)part[ps + j].x;
        atomicAdd(&cnt[p >> 17], 1);
    }
    __syncthreads();
    int own = cnt[tid];
    sums[tid] = own;
    __syncthreads();
    for (int off = 1; off < 512; off <<= 1) {
        int t = 0;
        if (tid >= off) t = sums[tid - off];
        __syncthreads();
        if (tid >= off) sums[tid] += t;
        __syncthreads();
    }
    int excl = sums[tid] - own;
    cnt[tid] = s + excl;              // running cursor (global position)
    if (tid < nrows) row_start[row0 + tid] = s + excl;
    if (b == NBUCK - 1 && tid == 0) row_start[N_NODES] = total;
    __syncthreads();
    for (int j = tid; j < cb; j += 512) {
        int2 r = part[ps + j];
        unsigned p = (unsigned)r.x;
        int pos = atomicAdd(&cnt[p >> 17], 1);
        csr_rec[pos] = make_int2((int)(p & 0x1FFFFu), r.y);
    }
}

// ---------- single-row gather: 8 bf16 cols per lane, chunk of 4 edges ----------
// RS = support row stride in shorts. Accumulates into a[] WITHOUT bias (bias added
// by caller afterward) to keep the hot-loop live set under 64 VGPR (8 blocks/CU).
template <int RS>
static __device__ __forceinline__ void row_gather(const unsigned short* __restrict__ supc,
                                                  const int2* __restrict__ csr_rec,
                                                  int s, int e, float a[8]) {
    if (s >= e) return;
    int2 r[4];
#pragma unroll
    for (int t = 0; t < 4; ++t) r[t] = csr_rec[min(s + t, e - 1)];
    for (int j = s; j < e; j += 4) {
        int4 sp[4];
#pragma unroll
        for (int t = 0; t < 4; ++t) sp[t] = *(const int4*)(supc + (size_t)r[t].x * RS);
        float wv[4];
#pragma unroll
        for (int t = 0; t < 4; ++t) wv[t] = (j + t < e) ? __int_as_float(r[t].y) : 0.0f;
        int jn = j + 4;
        if (jn < e) {
#pragma unroll
            for (int t = 0; t < 4; ++t) r[t] = csr_rec[min(jn + t, e - 1)];
        }
#pragma unroll
        for (int t = 0; t < 4; ++t) {
            float w = wv[t];
            int q[4] = {sp[t].x, sp[t].y, sp[t].z, sp[t].w};
#pragma unroll
            for (int c = 0; c < 4; ++c) {
                float flo = __uint_as_float(((unsigned)q[c]) << 16);
                float fhi = __uint_as_float(((unsigned)q[c]) & 0xffff0000u);
                a[2 * c]     += w * flo;
                a[2 * c + 1] += w * fhi;
            }
        }
    }
}

// ---------- MFMA GEMM (layer 1): one 64-row tile per block, A direct from global ----------
template <int K, int M, bool DYNIN>
__global__ __launch_bounds__(256, 8) void mgemm_kernel(const void* __restrict__ hv_,
                                                       const void* __restrict__ W,
                                                       unsigned short* __restrict__ out,
                                                       const int* __restrict__ flagp) {
    constexpr int KP = K + 8;
    constexpr int NC = M / 16;
    constexpr int NK = K / 32;

    __shared__ unsigned short wt[M][KP];  // W transposed

    const int bf = *flagp;
    const int tid = threadIdx.x;

    for (int i = tid; i < K * M; i += 256) {
        int k = i / M, m = i % M;
        wt[m][k] = f2bf(ldf(W, i, bf));
    }
    __syncthreads();

    const int lane = tid & 63;
    const int qd = lane >> 4;
    const int ln = lane & 15;
    const int wrow = (tid >> 6) * 16;
    const int tile = blockIdx.x;

    const int row = tile * 64 + wrow + ln;
    const bool ok = row < N_NODES;

    f32x4 acc[NC];
#pragma unroll
    for (int c = 0; c < NC; ++c) acc[c] = (f32x4){0.f, 0.f, 0.f, 0.f};

#pragma unroll
    for (int ks = 0; ks < NK; ++ks) {
        bf16x8 a;
        if (ok) {
            const size_t base = (size_t)row * K + ks * 32 + qd * 8;
            if (DYNIN && !bf) {
                const float* xp = (const float*)hv_ + base;
                float4 f0 = *(const float4*)xp;
                float4 f1 = *(const float4*)(xp + 4);
                ushort4 uu[2];
                uu[0].x = f2bf(f0.x); uu[0].y = f2bf(f0.y); uu[0].z = f2bf(f0.z); uu[0].w = f2bf(f0.w);
                uu[1].x = f2bf(f1.x); uu[1].y = f2bf(f1.y); uu[1].z = f2bf(f1.z); uu[1].w = f2bf(f1.w);
                a = *(const bf16x8*)uu;
            } else {
                a = *(const bf16x8*)((const unsigned short*)hv_ + base);
            }
        } else {
            a = (bf16x8)(__bf16)0.0f;
        }
#pragma unroll
        for (int c = 0; c < NC; ++c) {
            bf16x8 b = *(const bf16x8*)&wt[c * 16 + ln][ks * 32 + qd * 8];
            acc[c] = __builtin_amdgcn_mfma_f32_16x16x32_bf16(a, b, acc[c], 0, 0, 0);
        }
    }

#pragma unroll
    for (int c = 0; c < NC; ++c) {
#pragma unroll
        for (int r = 0; r < 4; ++r) {
            int orow = tile * 64 + wrow + qd * 4 + r;
            if (orow < N_NODES) out[(size_t)orow * M + c * 16 + ln] = f2bf(acc[c][r]);
        }
    }
}

// ---------- Fused: agg = relu(spmm(support)+bias); out = agg @ W  (K=64 fixed) ----------
// Gather: 32 groups x 8 lanes, 1 row per group per pass, 2 passes -> 64-row tile.
// Bias is applied AFTER the gather (slim hot-loop live set -> no spill at 64 VGPR).
template <int MOUT>
__global__ __launch_bounds__(256, 8) void fused_kernel(const unsigned short* __restrict__ support,
                                                       const int* __restrict__ row_start,
                                                       const int2* __restrict__ csr_rec,
                                                       const void* __restrict__ bias,
                                                       const void* __restrict__ W,
                                                       unsigned short* __restrict__ out,
                                                       const int* __restrict__ flagp) {
    constexpr int K = 64, KP = 72;
    constexpr int NC = MOUT / 16;
    constexpr int NK = 2;

    __shared__ unsigned short agg[64][KP];
    __shared__ unsigned short wt[MOUT][KP];

    const int bf = *flagp;
    const int tid = threadIdx.x;

    for (int i = tid; i < K * MOUT; i += 256) {
        int k = i / MOUT, m = i % MOUT;
        wt[m][k] = f2bf(ldf(W, i, bf));
    }
    // no barrier here: gather phase doesn't read wt; W-stage latency hides under gather

    const int lane = tid & 63;
    const int qd = lane >> 4;
    const int ln = lane & 15;
    const int wrow = (tid >> 6) * 16;

    const int grp = tid >> 3;   // 32 groups of 8 lanes; 1 row each per pass
    const int cc = tid & 7;     // cols cc*8..cc*8+7
    const unsigned short* supc = support + cc * 8;

    const int tile = blockIdx.x;
    const int rowA = tile * 64 + grp;
    const int rowB = rowA + 32;
    int s0 = row_start[min(rowA, N_NODES)];
    int e0 = row_start[min(rowA + 1, N_NODES)];
    int s1 = row_start[min(rowB, N_NODES)];
    int e1 = row_start[min(rowB + 1, N_NODES)];

    {
        float a[8];
#pragma unroll
        for (int c = 0; c < 8; ++c) a[c] = 0.0f;
        row_gather<64>(supc, csr_rec, s0, e0, a);
#pragma unroll
        for (int c = 0; c < 8; ++c) a[c] = fmaxf(a[c] + ldf(bias, cc * 8 + c, bf), 0.f);
        st8_half(&agg[grp][cc * 8], a);
    }
    {
        float a[8];
#pragma unroll
        for (int c = 0; c < 8; ++c) a[c] = 0.0f;
        row_gather<64>(supc, csr_rec, s1, e1, a);
#pragma unroll
        for (int c = 0; c < 8; ++c) a[c] = fmaxf(a[c] + ldf(bias, cc * 8 + c, bf), 0.f);
        st8_half(&agg[32 + grp][cc * 8], a);
    }
    __syncthreads();

    f32x4 macc[NC];
#pragma unroll
    for (int c = 0; c < NC; ++c) macc[c] = (f32x4){0.f, 0.f, 0.f, 0.f};
#pragma unroll
    for (int ks = 0; ks < NK; ++ks) {
        bf16x8 a = *(const bf16x8*)&agg[wrow + ln][ks * 32 + qd * 8];
#pragma unroll
        for (int c = 0; c < NC; ++c) {
            bf16x8 b = *(const bf16x8*)&wt[c * 16 + ln][ks * 32 + qd * 8];
            macc[c] = __builtin_amdgcn_mfma_f32_16x16x32_bf16(a, b, macc[c], 0, 0, 0);
        }
    }

#pragma unroll
    for (int c = 0; c < NC; ++c) {
#pragma unroll
        for (int r = 0; r < 4; ++r) {
            int orow = tile * 64 + wrow + qd * 4 + r;
            if (orow < N_NODES) out[(size_t)orow * MOUT + c * 16 + ln] = f2bf(macc[c][r]);
        }
    }
}

// ---------- final SpMM (M=16): 2 lanes x 16B per row, 1 row per group, 128 rows/block ----------
template <bool DYNOUT>
__global__ __launch_bounds__(256, 8) void spmm16_kernel(const unsigned short* __restrict__ support,
                                                        const int* __restrict__ row_start,
                                                        const int2* __restrict__ csr_rec,
                                                        const void* __restrict__ bias,
                                                        void* __restrict__ out_,
                                                        const int* __restrict__ flagp) {
    constexpr int M = 16;
    int bf = *flagp;
    int tid = threadIdx.x;
    int grp = tid >> 1;           // 128 groups x 1 row = 128 rows per block
    int cc = tid & 1;             // cols cc*8..cc*8+7
    int row = blockIdx.x * 128 + grp;
    if (row >= N_NODES) return;
    int s = row_start[row];
    int e = row_start[row + 1];
    float a[8];
#pragma unroll
    for (int c = 0; c < 8; ++c) a[c] = 0.0f;
    row_gather<16>(support + cc * 8, csr_rec, s, e, a);
#pragma unroll
    for (int c = 0; c < 8; ++c) a[c] += ldf(bias, cc * 8 + c, bf);
    if (DYNOUT && !bf) {
        float* op = (float*)out_ + (size_t)row * M + cc * 8;
        *(float4*)op = make_float4(a[0], a[1], a[2], a[3]);
        *(float4*)(op + 4) = make_float4(a[4], a[5], a[6], a[7]);
    } else {
        st8_half((unsigned short*)out_ + (size_t)row * M + cc * 8, a);
    }
}

extern "C" void kernel_launch(void* const* d_in, const int* in_sizes, int n_in,
                              void* d_out, int out_size, void* d_ws, size_t ws_size,
                              hipStream_t stream) {
    (void)in_sizes; (void)n_in; (void)out_size; (void)ws_size;
    const void* x  = d_in[0];
    const void* ev = d_in[1];
    const void* W1 = d_in[2];
    const void* b1 = d_in[3];
    const void* W2 = d_in[4];
    const void* b2 = d_in[5];
    const void* W3 = d_in[6];
    const void* b3 = d_in[7];
    const int* esrc = (const int*)d_in[8];
    const int* edst = (const int*)d_in[9];

    // workspace (~34 MB)
    char* ws = (char*)d_ws;
    size_t off = 0;
    auto alloc = [&](size_t bytes) -> void* {
        void* p = ws + off;
        off = (off + bytes + 255) & ~(size_t)255;
        return p;
    };
    unsigned short* A = (unsigned short*)alloc((size_t)N_NODES * 64 * 2);  // support1 / A3
    unsigned short* B = (unsigned short*)alloc((size_t)N_NODES * 64 * 2);  // A2
    int* row_start  = (int*)alloc((size_t)(N_NODES + 1) * 4);
    int* bcursor    = (int*)alloc(1024);
    int2* csr_rec   = (int2*)alloc((size_t)N_EDGES * 8);
    int* flagp      = (int*)alloc(256);
    // part[] (10.4 MB = 196*CAP*8) aliases A (12.8 MB): dead before mgemm1 writes A
    int2* part      = (int2*)A;

    // ---- dtype probe + cursor init ----
    detect_kernel<<<1, 256, 0, stream>>>((const unsigned short*)x, flagp, bcursor);

    // ---- CSR build: partition -> place (compact) ----
    part_kernel<<<(N_EDGES + 2047) / 2048, 256, 0, stream>>>(esrc, edst, ev, bcursor, part, flagp);
    place_kernel<<<NBUCK, 512, 0, stream>>>(bcursor, part, row_start, csr_rec);

    const int NT = (N_NODES + 63) / 64;  // 1563

    // ---- layer 1: A = x @ W1 ----
    mgemm_kernel<128, 64, true><<<NT, 256, 0, stream>>>(x, W1, A, flagp);
    // ---- layer 1 agg + layer 2 gemm fused: B = relu(spmm(A)+b1) @ W2 ----
    fused_kernel<64><<<NT, 256, 0, stream>>>(A, row_start, csr_rec, b1, W2, B, flagp);
    // ---- layer 2 agg + layer 3 gemm fused: A(=A3) = relu(spmm(B)+b2) @ W3 ----
    fused_kernel<16><<<NT, 256, 0, stream>>>(B, row_start, csr_rec, b2, W3, A, flagp);
    // ---- final aggregation: out = spmm(A3) + b3 ----
    spmm16_kernel<true><<<(N_NODES + 127) / 128, 256, 0, stream>>>(A, row_start, csr_rec, b3, d_out, flagp);
}